// Round 5
// baseline (129.259 us; speedup 1.0000x reference)
//
#include <hip/hip_runtime.h>
#include <math.h>

#define NG 128
#define NIN 512
#define OFF1 4194304   // 8192*512
#define OFF2 8388608   // 2*8192*512
#define OFF3 9437184   // OFF2 + 8192*128

#define INV_SQRT_2PI 0.3989422804014327f
#define INV_SQRT2    0.7071067811865476f

typedef float f32x4 __attribute__((ext_vector_type(4)));

// fast tanh: 1 - 2/(e^{2x}+1). v_exp_f32 + v_rcp_f32, ~2ulp.
__device__ __forceinline__ float ftanh(float x){
    float e = __expf(2.0f*x);
    float r = __builtin_amdgcn_rcpf(e + 1.0f);
    return 1.0f - 2.0f*r;
}
__device__ __forceinline__ float frcp(float x){ return __builtin_amdgcn_rcpf(x); }

// ============================================================================
// Kernel 1: forward-only dS/dt partials (k_pre folded in).
// 1024 blocks x 256 (R0-proven shape: 4 waves/SIMD); each half-block owns
// 4 rows, forward interleaved (16 independent tanh chains). Block d warms
// rows 8d..8d+7 in XCD (d%8)'s L2 -> k_main's swizzle reuses them.
// Block 0 publishes tv_ws + consts. Deterministic partials, NO atomics.
// ============================================================================
__global__ __launch_bounds__(256) void k_dsdt(const float* __restrict__ z,
    const float* __restrict__ Wx, const float* __restrict__ bx,
    const float* __restrict__ Wf, const float* __restrict__ bf,
    const float* __restrict__ Wo, const float* __restrict__ bo,
    const float* __restrict__ ts, const float* __restrict__ mup,
    const float* __restrict__ sigp,
    const float* __restrict__ Wt, const float* __restrict__ bt,
    const float* __restrict__ Wt2, const float* __restrict__ bt2,
    float* __restrict__ partial, float* __restrict__ tv_ws,
    float* __restrict__ consts){
    const int tid  = threadIdx.x;
    const int gidx = tid & 127;
    const int lb   = tid >> 7;

    // ---- per-group weights ----
    float wx[16], wf[16];
    #pragma unroll
    for (int i=0;i<4;i++){
        float4 a4 = ((const float4*)(Wx + gidx*16))[i];
        wx[i*4+0]=a4.x; wx[i*4+1]=a4.y; wx[i*4+2]=a4.z; wx[i*4+3]=a4.w;
        float4 b4 = ((const float4*)(Wf + gidx*16))[i];
        wf[i*4+0]=b4.x; wf[i*4+1]=b4.y; wf[i*4+2]=b4.z; wf[i*4+3]=b4.w;
    }
    float4 t4;
    t4 = ((const float4*)bx)[gidx];     float bxA[4]={t4.x,t4.y,t4.z,t4.w};
    t4 = ((const float4*)bf)[gidx];     float bfA[4]={t4.x,t4.y,t4.z,t4.w};
    t4 = ((const float4*)Wo)[gidx];     float w3[4] ={t4.x,t4.y,t4.z,t4.w};
    const float bo0 = bo[gidx];

    // ---- inline time-MLP: tv, dtv (was k_pre) ----
    const float t = ts[0];
    float tvA[4], w3wd[4];   // w3wd[i] = w3[i] * (wf_row_i . dtv)
    {
        const float f1 = 0.01f;                 // freqs = [1, 0.01] exactly
        float s0, c0, s1, c1;
        __sincosf(t, &s0, &c0);
        __sincosf(t*f1, &s1, &c1);
        float temb[4]  = { s0, s1, c0, c1 };
        float dtemb[4] = { c0, f1*c1, -s0, -f1*s1 };
        float tg[4], dg[4];
        #pragma unroll
        for (int i=0;i<4;i++){
            float a = bt[gidx*4+i], d = 0.0f;
            #pragma unroll
            for (int j=0;j<4;j++){
                float w = Wt[gidx*16+i*4+j];
                a += w*temb[j]; d += w*dtemb[j];
            }
            float E = erff(a*INV_SQRT2);
            tg[i] = 0.5f*a*(1.0f+E);
            dg[i] = (0.5f*(1.0f+E) + a*INV_SQRT_2PI*__expf(-0.5f*a*a))*d;
        }
        float dtvA[4];
        #pragma unroll
        for (int j=0;j<4;j++){
            float a = bt2[gidx*4+j], d = 0.0f;
            #pragma unroll
            for (int i=0;i<4;i++){
                float w = Wt2[gidx*16+j*4+i];
                a += w*tg[i]; d += w*dg[i];
            }
            tvA[j]  = a;
            dtvA[j] = d;
        }
        #pragma unroll
        for (int i=0;i<4;i++){
            float wd = wf[i*4]*dtvA[0]+wf[i*4+1]*dtvA[1]
                     + wf[i*4+2]*dtvA[2]+wf[i*4+3]*dtvA[3];
            w3wd[i] = w3[i]*wd;
        }
    }

    // ---- block 0 publishes tv_ws + consts for k_main ----
    if (blockIdx.x == 0){
        if (tid < 128){
            f32x4 tvv = { tvA[0], tvA[1], tvA[2], tvA[3] };
            *((f32x4*)(tv_ws + tid*4)) = tvv;
        }
        if (tid == 0){
            float mu = mup[0], sigma = sigp[0];
            float sig2  = sigma*sigma + 1e-5f;
            float phi_b = 0.5f*(1.0f+erff((10.0f-mu)/sigma*INV_SQRT2));
            float phi_a = 0.5f*(1.0f+erff((-10.0f-mu)/sigma*INV_SQRT2));
            consts[0] = sig2;
            consts[1] = -1.0f/sig2;                                    // dlp
            consts[2] = 1.0f/(sigma*sigma*sigma*sigma + 1e-5f);        // inv_s4
            consts[3] = 1.0f/(phi_b-phi_a);                            // invZ
            consts[4] = mu;
            consts[5] = 1.0f/sigma;
            consts[6] = sigma;
        }
    }

    const int r0 = blockIdx.x*8 + lb*4;

    // interleaved loads
    float zz[4][4];
    #pragma unroll
    for (int r=0;r<4;r++){
        float4 zv = *((const float4*)(z + (r0+r)*NIN + gidx*4));
        zz[r][0]=zv.x; zz[r][1]=zv.y; zz[r][2]=zv.z; zz[r][3]=zv.w;
    }
    // stage 1: 16 independent tanh
    float u1[4][4];
    #pragma unroll
    for (int r=0;r<4;r++){
        #pragma unroll
        for (int i=0;i<4;i++){
            float a = bxA[i] + wx[i*4]*zz[r][0]+wx[i*4+1]*zz[r][1]
                             + wx[i*4+2]*zz[r][2]+wx[i*4+3]*zz[r][3];
            u1[r][i] = ftanh(a) + tvA[i];
        }
    }
    // stage 2: 16 independent tanh
    float hp[4][4], a3[4];
    #pragma unroll
    for (int r=0;r<4;r++) a3[r] = bo0;
    #pragma unroll
    for (int r=0;r<4;r++){
        #pragma unroll
        for (int i=0;i<4;i++){
            float a = bfA[i] + wf[i*4]*u1[r][0]+wf[i*4+1]*u1[r][1]
                             + wf[i*4+2]*u1[r][2]+wf[i*4+3]*u1[r][3];
            float h = ftanh(a);
            hp[r][i] = 1.0f - h*h;
            a3[r] += w3[i]*h;
        }
    }
    // stage 3: 4 independent tanh + folded dSdt
    float acc = 0.0f;
    #pragma unroll
    for (int r=0;r<4;r++){
        float S = ftanh(a3[r]), sp = 1.0f - S*S;
        float dot = hp[r][0]*w3wd[0] + hp[r][1]*w3wd[1]
                  + hp[r][2]*w3wd[2] + hp[r][3]*w3wd[3];
        acc += sp*dot;
    }

    __shared__ float sred[256];
    sred[tid] = acc;
    __syncthreads();
    if (tid < 128) partial[blockIdx.x*128 + tid] = sred[tid] + sred[tid+128];
}

// Kernel 2: reduce 1024 partials per group -> dsum[g]. 128 blocks x 256.
__global__ __launch_bounds__(256) void k_red(const float* __restrict__ partial,
                                             float* __restrict__ dsum){
    int g = blockIdx.x;
    int tid = threadIdx.x;
    float a = 0.0f;
    for (int i=tid;i<1024;i+=256) a += partial[i*128+g];
    __shared__ float s[256];
    s[tid] = a;
    __syncthreads();
    if (tid < 64){
        a = s[tid] + s[tid+64] + s[tid+128] + s[tid+192];
        #pragma unroll
        for (int o=32;o>0;o>>=1) a += __shfl_down(a, o);
        if (tid==0) dsum[g] = a;
    }
}

// Kernel 3: full computation. 4096 blocks x 256; thread = (g) x 1 row.
// XCD-aligned swizzle: physical block p -> logical m with (m/4)%8 == p%8,
// so this block lands on the XCD whose L2 k_dsdt warmed with its 2 rows
// of z (rows 8d..8d+7 warmed by k_dsdt block d on XCD d%8; our rows
// 2m,2m+1 lie in chunk m/4). Speed-only assumption (round-robin p->XCD);
// worst case identical to unswizzled. Math bit-identical to round 4.
__global__ __launch_bounds__(256) void k_main(const float* __restrict__ z,
    const float* __restrict__ Wx, const float* __restrict__ bx,
    const float* __restrict__ Wf, const float* __restrict__ bf,
    const float* __restrict__ Wo, const float* __restrict__ bo,
    const float* __restrict__ betap, const float* __restrict__ tv_ws,
    const float* __restrict__ consts,
    const float* __restrict__ dsum, float* __restrict__ out){
    const int tid  = threadIdx.x;
    const int gidx = tid & 127;

    const int p    = blockIdx.x;
    const int xcd  = p & 7;
    const int slot = p >> 3;                    // 0..511
    const int m    = 32*(slot>>2) + 4*xcd + (slot&3);   // bijective remap
    const int row  = m*2 + (tid>>7);

    // z load first: the only HBM/L2-latency load
    float zz[4];
    {
        float4 zv = *((const float4*)(z + row*NIN + gidx*4));
        zz[0]=zv.x; zz[1]=zv.y; zz[2]=zv.z; zz[3]=zv.w;
    }

    const float sig2    = consts[0];
    const float dlp     = consts[1];
    const float inv_s4  = consts[2];
    const float invZ    = consts[3];
    const float mu      = consts[4];
    const float inv_sig = consts[5];
    const float sigma   = consts[6];
    const float inv_sig2 = frcp(sig2);

    float wx[16], wf[16];
    #pragma unroll
    for (int i=0;i<4;i++){
        float4 a4 = ((const float4*)(Wx + gidx*16))[i];
        wx[i*4+0]=a4.x; wx[i*4+1]=a4.y; wx[i*4+2]=a4.z; wx[i*4+3]=a4.w;
        float4 b4 = ((const float4*)(Wf + gidx*16))[i];
        wf[i*4+0]=b4.x; wf[i*4+1]=b4.y; wf[i*4+2]=b4.z; wf[i*4+3]=b4.w;
    }
    float4 t4;
    t4 = ((const float4*)bx)[gidx];    float bxA[4]={t4.x,t4.y,t4.z,t4.w};
    t4 = ((const float4*)bf)[gidx];    float bfA[4]={t4.x,t4.y,t4.z,t4.w};
    t4 = ((const float4*)Wo)[gidx];    float w3[4] ={t4.x,t4.y,t4.z,t4.w};
    t4 = ((const float4*)tv_ws)[gidx]; float tvA[4]={t4.x,t4.y,t4.z,t4.w};
    const float bo0    = bo[gidx];
    const float bb     = betap[gidx];
    const float dS_sum = dsum[gidx];
    const float bbdlp  = bb*dlp;
    const float b2     = 0.125f*bb*bb;

    // ---- forward ----
    float x_[4], xp[4], h_[4], hp[4], u1[4];
    #pragma unroll
    for (int i=0;i<4;i++){
        float a = bxA[i] + wx[i*4]*zz[0]+wx[i*4+1]*zz[1]
                         + wx[i*4+2]*zz[2]+wx[i*4+3]*zz[3];
        x_[i] = ftanh(a);
    }
    #pragma unroll
    for (int i=0;i<4;i++){
        xp[i] = 1.0f - x_[i]*x_[i];
        u1[i] = x_[i] + tvA[i];
    }
    float a3 = bo0;
    #pragma unroll
    for (int i=0;i<4;i++){
        float a = bfA[i] + wf[i*4]*u1[0]+wf[i*4+1]*u1[1]
                         + wf[i*4+2]*u1[2]+wf[i*4+3]*u1[3];
        h_[i] = ftanh(a);
    }
    #pragma unroll
    for (int i=0;i<4;i++){
        hp[i] = 1.0f - h_[i]*h_[i];
        a3 += w3[i]*h_[i];
    }
    const float S  = ftanh(a3);
    const float sp = 1.0f - S*S;
    float q[4] = {0,0,0,0};
    #pragma unroll
    for (int i=0;i<4;i++){
        float vi = sp*w3[i]*hp[i];
        #pragma unroll
        for (int j=0;j<4;j++) q[j] += vi*wf[i*4+j];
    }

    // ---- epilogue ----
    float wfxp[16];
    #pragma unroll
    for (int i=0;i<4;i++){
        #pragma unroll
        for (int k=0;k<4;k++) wfxp[i*4+k] = wf[i*4+k]*xp[k];
    }
    float Bm[16];
    #pragma unroll
    for (int i=0;i<4;i++){
        #pragma unroll
        for (int n=0;n<4;n++){
            float s = 0.0f;
            #pragma unroll
            for (int k=0;k<4;k++) s += wfxp[i*4+k]*wx[k*4+n];
            Bm[i*4+n]=s;
        }
    }
    float w3hp[4], v[4];
    #pragma unroll
    for (int i=0;i<4;i++){ w3hp[i]=w3[i]*hp[i]; v[i]=sp*w3hp[i]; }
    float c[4];
    #pragma unroll
    for (int n=0;n<4;n++){
        float s=0.0f;
        #pragma unroll
        for (int i=0;i<4;i++) s += w3hp[i]*Bm[i*4+n];
        c[n]=s;
    }
    const float alpha = -2.0f*S*sp;
    float bet[4], gam[4];
    #pragma unroll
    for (int i=0;i<4;i++){
        bet[i] = -2.0f*h_[i]*v[i];
        gam[i] = -2.0f*x_[i]*xp[i]*q[i];
    }

    float rho[4], nlp[4], dpp[4];
    #pragma unroll
    for (int j=0;j<4;j++){
        float zj = zz[j];
        float xs = zj > 10.0f ? zj+100.0f : zj;
        xs = xs < -10.0f ? xs-100.0f : xs;
        float xn = (xs-mu)*inv_sig;
        float dens = __expf(-0.5f*xn*xn)*INV_SQRT_2PI;
        dens = (xn > 10.0f || xn < -10.0f) ? 0.0f : dens;
        rho[j] = dens*invZ + 1e-10f;
        nlp[j] = -(zj-mu)*inv_sig2;
        float d = zj-mu;
        dpp[j] = (d*d - sigma*sigma)*inv_s4;
    }
    float u_val = S - bb*__logf(rho[0]*rho[1]*rho[2]*rho[3]);

    float rc=0.0f, scs=0.0f;
    #pragma unroll
    for (int j=0;j<4;j++){ rc += rho[j]*c[j]; scs += c[j]; }
    float rB[4], sB[4], rA[4], sA[4];
    #pragma unroll
    for (int i=0;i<4;i++){
        float r1=0.0f, s=0.0f, r2=0.0f, s2=0.0f;
        #pragma unroll
        for (int j=0;j<4;j++){
            r1 += rho[j]*Bm[i*4+j]; s  += Bm[i*4+j];
            r2 += rho[j]*wx[i*4+j]; s2 += wx[i*4+j];
        }
        rB[i]=r1; sB[i]=s; rA[i]=r2; sA[i]=s2;
    }

    const float arc  = alpha*rc;
    const float ascs = alpha*scs;
    float brB[4], bsB[4], grA[4], gsA[4];
    #pragma unroll
    for (int i=0;i<4;i++){
        brB[i] = bet[i]*rB[i];  bsB[i] = bet[i]*sB[i];
        grA[i] = gam[i]*rA[i];  gsA[i] = gam[i]*sA[i];
    }

    float pde[4], uz[4], uzz[4];
    #pragma unroll
    for (int k=0;k<4;k++){
        float corr = arc*c[k];
        float hsum = ascs*c[k];
        #pragma unroll
        for (int i=0;i<4;i++){
            corr += brB[i]*Bm[i*4+k];
            hsum += bsB[i]*Bm[i*4+k];
            corr += grA[i]*wx[i*4+k];
            hsum += gsA[i]*wx[i*4+k];
        }
        float uzk = sp*c[k] - bb*nlp[k];
        uz[k]  = uzk;
        uzz[k] = hsum - bbdlp;
        pde[k] = dS_sum + bb*corr*frcp(rho[k]+1e-5f)
               + 0.5f*uzk*uzk + b2*(nlp[k]*nlp[k] - 2.0f*dpp[k]);
    }

    const int base = row*NIN + gidx*4;
    f32x4 pdev = { pde[0], pde[1], pde[2], pde[3] };
    f32x4 uzv  = { uz[0],  uz[1],  uz[2],  uz[3]  };
    f32x4 uzzv = { uzz[0], uzz[1], uzz[2], uzz[3] };
    __builtin_nontemporal_store(pdev, (f32x4*)(out + base));
    __builtin_nontemporal_store(uzv,  (f32x4*)(out + OFF1 + base));
    __builtin_nontemporal_store(u_val, out + OFF2 + row*NG + gidx);
    __builtin_nontemporal_store(uzzv, (f32x4*)(out + OFF3 + base));
}

extern "C" void kernel_launch(void* const* d_in, const int* in_sizes, int n_in,
                              void* d_out, int out_size, void* d_ws, size_t ws_size,
                              hipStream_t stream){
    (void)in_sizes; (void)n_in; (void)out_size; (void)ws_size;
    const float* z     = (const float*)d_in[0];
    const float* ts    = (const float*)d_in[1];
    const float* mu    = (const float*)d_in[2];
    const float* sigma = (const float*)d_in[3];
    const float* Wx    = (const float*)d_in[4];
    const float* bx    = (const float*)d_in[5];
    const float* Wt    = (const float*)d_in[6];
    const float* bt    = (const float*)d_in[7];
    const float* Wt2   = (const float*)d_in[8];
    const float* bt2   = (const float*)d_in[9];
    const float* Wf    = (const float*)d_in[10];
    const float* bf    = (const float*)d_in[11];
    const float* Wo    = (const float*)d_in[12];
    const float* bo    = (const float*)d_in[13];
    const float* beta  = (const float*)d_in[14];
    float* out = (float*)d_out;

    float* ws      = (float*)d_ws;
    float* tv_ws   = ws;            // 512
    float* consts  = ws + 512;      // 8
    float* dsum    = ws + 520;      // 128
    float* partial = ws + 648;      // 1024*128 = 131072

    k_dsdt<<<1024,256, 0, stream>>>(z, Wx, bx, Wf, bf, Wo, bo,
                                    ts, mu, sigma, Wt, bt, Wt2, bt2,
                                    partial, tv_ws, consts);
    k_red <<<128, 256, 0, stream>>>(partial, dsum);
    k_main<<<4096,256, 0, stream>>>(z, Wx, bx, Wf, bf, Wo, bo, beta, tv_ws,
                                    consts, dsum, out);
}

// Round 6
// 125.748 us; speedup vs baseline: 1.0279x; 1.0279x over previous
//
#include <hip/hip_runtime.h>
#include <math.h>

#define NG 128
#define NIN 512
#define OFF1 4194304   // 8192*512
#define OFF2 8388608   // 2*8192*512
#define OFF3 9437184   // OFF2 + 8192*128

#define INV_SQRT_2PI 0.3989422804014327f
#define INV_SQRT2    0.7071067811865476f

typedef float f32x4 __attribute__((ext_vector_type(4)));

// fast tanh: 1 - 2/(e^{2x}+1). v_exp_f32 + v_rcp_f32, ~2ulp.
__device__ __forceinline__ float ftanh(float x){
    float e = __expf(2.0f*x);
    float r = __builtin_amdgcn_rcpf(e + 1.0f);
    return 1.0f - 2.0f*r;
}
__device__ __forceinline__ float frcp(float x){ return __builtin_amdgcn_rcpf(x); }

// ============================================================================
// Kernel 1: forward-only dS/dt partials (k_pre folded in).
// 512 blocks x 256; each half-block (128 thr) owns 8 rows, processed as
// two 4-row batches (16 independent tanh chains in flight; VGPR capped).
// Prologue (weights + time-MLP incl. erf) amortized over 8 rows.
// Block 0 publishes tv_ws + consts for k_main. Deterministic per-block
// partials, NO atomics.
// ============================================================================
__global__ __launch_bounds__(256) void k_dsdt(const float* __restrict__ z,
    const float* __restrict__ Wx, const float* __restrict__ bx,
    const float* __restrict__ Wf, const float* __restrict__ bf,
    const float* __restrict__ Wo, const float* __restrict__ bo,
    const float* __restrict__ ts, const float* __restrict__ mup,
    const float* __restrict__ sigp,
    const float* __restrict__ Wt, const float* __restrict__ bt,
    const float* __restrict__ Wt2, const float* __restrict__ bt2,
    float* __restrict__ partial, float* __restrict__ tv_ws,
    float* __restrict__ consts){
    const int tid  = threadIdx.x;
    const int gidx = tid & 127;
    const int lb   = tid >> 7;

    // ---- per-group weights ----
    float wx[16], wf[16];
    #pragma unroll
    for (int i=0;i<4;i++){
        float4 a4 = ((const float4*)(Wx + gidx*16))[i];
        wx[i*4+0]=a4.x; wx[i*4+1]=a4.y; wx[i*4+2]=a4.z; wx[i*4+3]=a4.w;
        float4 b4 = ((const float4*)(Wf + gidx*16))[i];
        wf[i*4+0]=b4.x; wf[i*4+1]=b4.y; wf[i*4+2]=b4.z; wf[i*4+3]=b4.w;
    }
    float4 t4;
    t4 = ((const float4*)bx)[gidx];     float bxA[4]={t4.x,t4.y,t4.z,t4.w};
    t4 = ((const float4*)bf)[gidx];     float bfA[4]={t4.x,t4.y,t4.z,t4.w};
    t4 = ((const float4*)Wo)[gidx];     float w3[4] ={t4.x,t4.y,t4.z,t4.w};
    const float bo0 = bo[gidx];

    // ---- inline time-MLP: tv, dtv (was k_pre) ----
    const float t = ts[0];
    float tvA[4], w3wd[4];   // w3wd[i] = w3[i] * (wf_row_i . dtv)
    {
        const float f1 = 0.01f;                 // freqs = [1, 0.01] exactly
        float s0, c0, s1, c1;
        __sincosf(t, &s0, &c0);
        __sincosf(t*f1, &s1, &c1);
        float temb[4]  = { s0, s1, c0, c1 };
        float dtemb[4] = { c0, f1*c1, -s0, -f1*s1 };
        float tg[4], dg[4];
        #pragma unroll
        for (int i=0;i<4;i++){
            float a = bt[gidx*4+i], d = 0.0f;
            #pragma unroll
            for (int j=0;j<4;j++){
                float w = Wt[gidx*16+i*4+j];
                a += w*temb[j]; d += w*dtemb[j];
            }
            float E = erff(a*INV_SQRT2);
            tg[i] = 0.5f*a*(1.0f+E);
            dg[i] = (0.5f*(1.0f+E) + a*INV_SQRT_2PI*__expf(-0.5f*a*a))*d;
        }
        float dtvA[4];
        #pragma unroll
        for (int j=0;j<4;j++){
            float a = bt2[gidx*4+j], d = 0.0f;
            #pragma unroll
            for (int i=0;i<4;i++){
                float w = Wt2[gidx*16+j*4+i];
                a += w*tg[i]; d += w*dg[i];
            }
            tvA[j]  = a;
            dtvA[j] = d;
        }
        #pragma unroll
        for (int i=0;i<4;i++){
            float wd = wf[i*4]*dtvA[0]+wf[i*4+1]*dtvA[1]
                     + wf[i*4+2]*dtvA[2]+wf[i*4+3]*dtvA[3];
            w3wd[i] = w3[i]*wd;
        }
    }

    // ---- block 0 publishes tv_ws + consts for k_main ----
    if (blockIdx.x == 0){
        if (tid < 128){
            f32x4 tvv = { tvA[0], tvA[1], tvA[2], tvA[3] };
            *((f32x4*)(tv_ws + tid*4)) = tvv;
        }
        if (tid == 0){
            float mu = mup[0], sigma = sigp[0];
            float sig2  = sigma*sigma + 1e-5f;
            float phi_b = 0.5f*(1.0f+erff((10.0f-mu)/sigma*INV_SQRT2));
            float phi_a = 0.5f*(1.0f+erff((-10.0f-mu)/sigma*INV_SQRT2));
            consts[0] = sig2;
            consts[1] = -1.0f/sig2;                                    // dlp
            consts[2] = 1.0f/(sigma*sigma*sigma*sigma + 1e-5f);        // inv_s4
            consts[3] = 1.0f/(phi_b-phi_a);                            // invZ
            consts[4] = mu;
            consts[5] = 1.0f/sigma;
            consts[6] = sigma;
        }
    }

    const int rbase = blockIdx.x*16 + lb*8;    // 8 rows per half-block

    float acc = 0.0f;
    #pragma unroll
    for (int half=0; half<2; half++){
        const int r0 = rbase + half*4;
        // interleaved loads
        float zz[4][4];
        #pragma unroll
        for (int r=0;r<4;r++){
            float4 zv = *((const float4*)(z + (r0+r)*NIN + gidx*4));
            zz[r][0]=zv.x; zz[r][1]=zv.y; zz[r][2]=zv.z; zz[r][3]=zv.w;
        }
        // stage 1: 16 independent tanh
        float u1[4][4];
        #pragma unroll
        for (int r=0;r<4;r++){
            #pragma unroll
            for (int i=0;i<4;i++){
                float a = bxA[i] + wx[i*4]*zz[r][0]+wx[i*4+1]*zz[r][1]
                                 + wx[i*4+2]*zz[r][2]+wx[i*4+3]*zz[r][3];
                u1[r][i] = ftanh(a) + tvA[i];
            }
        }
        // stage 2: 16 independent tanh
        float hp[4][4], a3[4];
        #pragma unroll
        for (int r=0;r<4;r++) a3[r] = bo0;
        #pragma unroll
        for (int r=0;r<4;r++){
            #pragma unroll
            for (int i=0;i<4;i++){
                float a = bfA[i] + wf[i*4]*u1[r][0]+wf[i*4+1]*u1[r][1]
                                 + wf[i*4+2]*u1[r][2]+wf[i*4+3]*u1[r][3];
                float h = ftanh(a);
                hp[r][i] = 1.0f - h*h;
                a3[r] += w3[i]*h;
            }
        }
        // stage 3: 4 independent tanh + folded dSdt
        #pragma unroll
        for (int r=0;r<4;r++){
            float S = ftanh(a3[r]), sp = 1.0f - S*S;
            float dot = hp[r][0]*w3wd[0] + hp[r][1]*w3wd[1]
                      + hp[r][2]*w3wd[2] + hp[r][3]*w3wd[3];
            acc += sp*dot;
        }
    }

    __shared__ float sred[256];
    sred[tid] = acc;
    __syncthreads();
    if (tid < 128) partial[blockIdx.x*128 + tid] = sred[tid] + sred[tid+128];
}

// Kernel 2: reduce 512 partials per group -> dsum[g]. 128 blocks x 256.
__global__ __launch_bounds__(256) void k_red(const float* __restrict__ partial,
                                             float* __restrict__ dsum){
    int g = blockIdx.x;
    int tid = threadIdx.x;
    float a = 0.0f;
    for (int i=tid;i<512;i+=256) a += partial[i*128+g];
    __shared__ float s[256];
    s[tid] = a;
    __syncthreads();
    if (tid < 64){
        a = s[tid] + s[tid+64] + s[tid+128] + s[tid+192];
        #pragma unroll
        for (int o=32;o>0;o>>=1) a += __shfl_down(a, o);
        if (tid==0) dsum[g] = a;
    }
}

// Kernel 3: full computation. 4096 blocks x 256; thread = (g) x 1 row.
// 1 row/thread minimizes live state (~100 VGPR) -> 4-5 waves/SIMD for
// latency hiding of the exp/rcp dependent chains.
__global__ __launch_bounds__(256) void k_main(const float* __restrict__ z,
    const float* __restrict__ Wx, const float* __restrict__ bx,
    const float* __restrict__ Wf, const float* __restrict__ bf,
    const float* __restrict__ Wo, const float* __restrict__ bo,
    const float* __restrict__ betap, const float* __restrict__ tv_ws,
    const float* __restrict__ consts,
    const float* __restrict__ dsum, float* __restrict__ out){
    const int tid  = threadIdx.x;
    const int gidx = tid & 127;
    const int row  = blockIdx.x*2 + (tid>>7);

    // z load first: the only HBM-latency load (weights are L2-hot)
    float zz[4];
    {
        float4 zv = *((const float4*)(z + row*NIN + gidx*4));
        zz[0]=zv.x; zz[1]=zv.y; zz[2]=zv.z; zz[3]=zv.w;
    }

    const float sig2    = consts[0];
    const float dlp     = consts[1];
    const float inv_s4  = consts[2];
    const float invZ    = consts[3];
    const float mu      = consts[4];
    const float inv_sig = consts[5];
    const float sigma   = consts[6];
    const float inv_sig2 = frcp(sig2);

    float wx[16], wf[16];
    #pragma unroll
    for (int i=0;i<4;i++){
        float4 a4 = ((const float4*)(Wx + gidx*16))[i];
        wx[i*4+0]=a4.x; wx[i*4+1]=a4.y; wx[i*4+2]=a4.z; wx[i*4+3]=a4.w;
        float4 b4 = ((const float4*)(Wf + gidx*16))[i];
        wf[i*4+0]=b4.x; wf[i*4+1]=b4.y; wf[i*4+2]=b4.z; wf[i*4+3]=b4.w;
    }
    float4 t4;
    t4 = ((const float4*)bx)[gidx];    float bxA[4]={t4.x,t4.y,t4.z,t4.w};
    t4 = ((const float4*)bf)[gidx];    float bfA[4]={t4.x,t4.y,t4.z,t4.w};
    t4 = ((const float4*)Wo)[gidx];    float w3[4] ={t4.x,t4.y,t4.z,t4.w};
    t4 = ((const float4*)tv_ws)[gidx]; float tvA[4]={t4.x,t4.y,t4.z,t4.w};
    const float bo0    = bo[gidx];
    const float bb     = betap[gidx];
    const float dS_sum = dsum[gidx];
    const float bbdlp  = bb*dlp;
    const float b2     = 0.125f*bb*bb;

    // ---- forward ----
    float x_[4], xp[4], h_[4], hp[4], u1[4];
    #pragma unroll
    for (int i=0;i<4;i++){
        float a = bxA[i] + wx[i*4]*zz[0]+wx[i*4+1]*zz[1]
                         + wx[i*4+2]*zz[2]+wx[i*4+3]*zz[3];
        x_[i] = ftanh(a);
    }
    #pragma unroll
    for (int i=0;i<4;i++){
        xp[i] = 1.0f - x_[i]*x_[i];
        u1[i] = x_[i] + tvA[i];
    }
    float a3 = bo0;
    #pragma unroll
    for (int i=0;i<4;i++){
        float a = bfA[i] + wf[i*4]*u1[0]+wf[i*4+1]*u1[1]
                         + wf[i*4+2]*u1[2]+wf[i*4+3]*u1[3];
        h_[i] = ftanh(a);
    }
    #pragma unroll
    for (int i=0;i<4;i++){
        hp[i] = 1.0f - h_[i]*h_[i];
        a3 += w3[i]*h_[i];
    }
    const float S  = ftanh(a3);
    const float sp = 1.0f - S*S;
    float q[4] = {0,0,0,0};
    #pragma unroll
    for (int i=0;i<4;i++){
        float vi = sp*w3[i]*hp[i];
        #pragma unroll
        for (int j=0;j<4;j++) q[j] += vi*wf[i*4+j];
    }

    // ---- epilogue ----
    float wfxp[16];
    #pragma unroll
    for (int i=0;i<4;i++){
        #pragma unroll
        for (int k=0;k<4;k++) wfxp[i*4+k] = wf[i*4+k]*xp[k];
    }
    float Bm[16];
    #pragma unroll
    for (int i=0;i<4;i++){
        #pragma unroll
        for (int n=0;n<4;n++){
            float s = 0.0f;
            #pragma unroll
            for (int k=0;k<4;k++) s += wfxp[i*4+k]*wx[k*4+n];
            Bm[i*4+n]=s;
        }
    }
    float w3hp[4], v[4];
    #pragma unroll
    for (int i=0;i<4;i++){ w3hp[i]=w3[i]*hp[i]; v[i]=sp*w3hp[i]; }
    float c[4];
    #pragma unroll
    for (int n=0;n<4;n++){
        float s=0.0f;
        #pragma unroll
        for (int i=0;i<4;i++) s += w3hp[i]*Bm[i*4+n];
        c[n]=s;
    }
    const float alpha = -2.0f*S*sp;
    float bet[4], gam[4];
    #pragma unroll
    for (int i=0;i<4;i++){
        bet[i] = -2.0f*h_[i]*v[i];
        gam[i] = -2.0f*x_[i]*xp[i]*q[i];
    }

    float rho[4], nlp[4], dpp[4];
    #pragma unroll
    for (int j=0;j<4;j++){
        float zj = zz[j];
        float xs = zj > 10.0f ? zj+100.0f : zj;
        xs = xs < -10.0f ? xs-100.0f : xs;
        float xn = (xs-mu)*inv_sig;
        float dens = __expf(-0.5f*xn*xn)*INV_SQRT_2PI;
        dens = (xn > 10.0f || xn < -10.0f) ? 0.0f : dens;
        rho[j] = dens*invZ + 1e-10f;
        nlp[j] = -(zj-mu)*inv_sig2;
        float d = zj-mu;
        dpp[j] = (d*d - sigma*sigma)*inv_s4;
    }
    float u_val = S - bb*__logf(rho[0]*rho[1]*rho[2]*rho[3]);

    float rc=0.0f, scs=0.0f;
    #pragma unroll
    for (int j=0;j<4;j++){ rc += rho[j]*c[j]; scs += c[j]; }
    float rB[4], sB[4], rA[4], sA[4];
    #pragma unroll
    for (int i=0;i<4;i++){
        float r1=0.0f, s=0.0f, r2=0.0f, s2=0.0f;
        #pragma unroll
        for (int j=0;j<4;j++){
            r1 += rho[j]*Bm[i*4+j]; s  += Bm[i*4+j];
            r2 += rho[j]*wx[i*4+j]; s2 += wx[i*4+j];
        }
        rB[i]=r1; sB[i]=s; rA[i]=r2; sA[i]=s2;
    }

    const float arc  = alpha*rc;
    const float ascs = alpha*scs;
    float brB[4], bsB[4], grA[4], gsA[4];
    #pragma unroll
    for (int i=0;i<4;i++){
        brB[i] = bet[i]*rB[i];  bsB[i] = bet[i]*sB[i];
        grA[i] = gam[i]*rA[i];  gsA[i] = gam[i]*sA[i];
    }

    float pde[4], uz[4], uzz[4];
    #pragma unroll
    for (int k=0;k<4;k++){
        float corr = arc*c[k];
        float hsum = ascs*c[k];
        #pragma unroll
        for (int i=0;i<4;i++){
            corr += brB[i]*Bm[i*4+k];
            hsum += bsB[i]*Bm[i*4+k];
            corr += grA[i]*wx[i*4+k];
            hsum += gsA[i]*wx[i*4+k];
        }
        float uzk = sp*c[k] - bb*nlp[k];
        uz[k]  = uzk;
        uzz[k] = hsum - bbdlp;
        pde[k] = dS_sum + bb*corr*frcp(rho[k]+1e-5f)
               + 0.5f*uzk*uzk + b2*(nlp[k]*nlp[k] - 2.0f*dpp[k]);
    }

    const int base = row*NIN + gidx*4;
    f32x4 pdev = { pde[0], pde[1], pde[2], pde[3] };
    f32x4 uzv  = { uz[0],  uz[1],  uz[2],  uz[3]  };
    f32x4 uzzv = { uzz[0], uzz[1], uzz[2], uzz[3] };
    __builtin_nontemporal_store(pdev, (f32x4*)(out + base));
    __builtin_nontemporal_store(uzv,  (f32x4*)(out + OFF1 + base));
    __builtin_nontemporal_store(u_val, out + OFF2 + row*NG + gidx);
    __builtin_nontemporal_store(uzzv, (f32x4*)(out + OFF3 + base));
}

extern "C" void kernel_launch(void* const* d_in, const int* in_sizes, int n_in,
                              void* d_out, int out_size, void* d_ws, size_t ws_size,
                              hipStream_t stream){
    (void)in_sizes; (void)n_in; (void)out_size; (void)ws_size;
    const float* z     = (const float*)d_in[0];
    const float* ts    = (const float*)d_in[1];
    const float* mu    = (const float*)d_in[2];
    const float* sigma = (const float*)d_in[3];
    const float* Wx    = (const float*)d_in[4];
    const float* bx    = (const float*)d_in[5];
    const float* Wt    = (const float*)d_in[6];
    const float* bt    = (const float*)d_in[7];
    const float* Wt2   = (const float*)d_in[8];
    const float* bt2   = (const float*)d_in[9];
    const float* Wf    = (const float*)d_in[10];
    const float* bf    = (const float*)d_in[11];
    const float* Wo    = (const float*)d_in[12];
    const float* bo    = (const float*)d_in[13];
    const float* beta  = (const float*)d_in[14];
    float* out = (float*)d_out;

    float* ws      = (float*)d_ws;
    float* tv_ws   = ws;            // 512
    float* consts  = ws + 512;      // 8
    float* dsum    = ws + 520;      // 128
    float* partial = ws + 648;      // 512*128 = 65536

    k_dsdt<<<512, 256, 0, stream>>>(z, Wx, bx, Wf, bf, Wo, bo,
                                    ts, mu, sigma, Wt, bt, Wt2, bt2,
                                    partial, tv_ws, consts);
    k_red <<<128, 256, 0, stream>>>(partial, dsum);
    k_main<<<4096,256, 0, stream>>>(z, Wx, bx, Wf, bf, Wo, bo, beta, tv_ws,
                                    consts, dsum, out);
}